// Round 1
// baseline (521.085 us; speedup 1.0000x reference)
//
#include <hip/hip_runtime.h>
#include <math.h>

#define BB 32
#define TQQ 2000
#define TKK 512
#define CR 8            // rows (time steps) per chunk
#define RS 8            // ring slots, in chunks (fused fallback)
#define NW 8            // fused fallback: 2 consumer waves + 6 producer waves
#define SLOT_F 520      // floats per row slot: p[0..511], pb at 512, pad to 520
#define BRN 32          // boundary ring entries (4 chunks)
#define WSROW 520       // workspace row stride in floats
#define SMC 4           // softmax kernel: waves per block

__device__ __forceinline__ float dpp_mv_111(float x, float old) {
    return __int_as_float(__builtin_amdgcn_update_dpp(__float_as_int(old), __float_as_int(x), 0x111, 0xf, 0xf, false));
}
__device__ __forceinline__ float dpp_mv_112(float x, float old) {
    return __int_as_float(__builtin_amdgcn_update_dpp(__float_as_int(old), __float_as_int(x), 0x112, 0xf, 0xf, false));
}
__device__ __forceinline__ float dpp_mv_114(float x, float old) {
    return __int_as_float(__builtin_amdgcn_update_dpp(__float_as_int(old), __float_as_int(x), 0x114, 0xf, 0xf, false));
}
__device__ __forceinline__ float dpp_mv_118(float x, float old) {
    return __int_as_float(__builtin_amdgcn_update_dpp(__float_as_int(old), __float_as_int(x), 0x118, 0xf, 0xf, false));
}
__device__ __forceinline__ float dpp_mv_b15(float x, float old) {
    return __int_as_float(__builtin_amdgcn_update_dpp(__float_as_int(old), __float_as_int(x), 0x142, 0xf, 0xf, false));
}
__device__ __forceinline__ float dpp_mv_b31(float x, float old) {
    return __int_as_float(__builtin_amdgcn_update_dpp(__float_as_int(old), __float_as_int(x), 0x143, 0xf, 0xf, false));
}
__device__ __forceinline__ float dpp_wave_shr1(float x, float old) {
    return __int_as_float(__builtin_amdgcn_update_dpp(__float_as_int(old), __float_as_int(x), 0x138, 0xf, 0xf, false));
}

__device__ __forceinline__ float wred_max(float x) {
    x = fmaxf(x, dpp_mv_111(x, -1e38f));
    x = fmaxf(x, dpp_mv_112(x, -1e38f));
    x = fmaxf(x, dpp_mv_114(x, -1e38f));
    x = fmaxf(x, dpp_mv_118(x, -1e38f));
    x = fmaxf(x, dpp_mv_b15(x, -1e38f));
    x = fmaxf(x, dpp_mv_b31(x, -1e38f));
    return __int_as_float(__builtin_amdgcn_readlane(__float_as_int(x), 63));
}
__device__ __forceinline__ float wred_sum(float x) {
    x += dpp_mv_111(x, 0.0f);
    x += dpp_mv_112(x, 0.0f);
    x += dpp_mv_114(x, 0.0f);
    x += dpp_mv_118(x, 0.0f);
    x += dpp_mv_b15(x, 0.0f);
    x += dpp_mv_b31(x, 0.0f);
    return __int_as_float(__builtin_amdgcn_readlane(__float_as_int(x), 63));
}

__device__ __forceinline__ float pow2i(int e) {    // e in [-126, 127]
    return __int_as_float((unsigned)(e + 127) << 23);
}

// one DP step over 4 state-pairs/lane; uses OLD O[i-1] (descending order)
__device__ __forceinline__ void step_quad(float4 p, float pb, float o_prev,
                                          float E[4], float O[4]) {
    float t3 = E[3] + O[2];  O[3] = (O[3] + t3) * p.w;  E[3] = t3 * pb;
    float t2 = E[2] + O[1];  O[2] = (O[2] + t2) * p.z;  E[2] = t2 * pb;
    float t1 = E[1] + O[0];  O[1] = (O[1] + t1) * p.y;  E[1] = t1 * pb;
    float t0 = E[0] + o_prev; O[0] = (O[0] + t0) * p.x; E[0] = t0 * pb;
}

// exact per-element mask: p[m] := (m < kl) ? p[m] : 0   (select, NOT multiply,
// so uninitialized-workspace NaN/Inf cannot propagate)
__device__ __forceinline__ float4 selp4(float4 p, int m0, int kl) {
    p.x = (m0 + 0 < kl) ? p.x : 0.f;
    p.y = (m0 + 1 < kl) ? p.y : 0.f;
    p.z = (m0 + 2 < kl) ? p.z : 0.f;
    p.w = (m0 + 3 < kl) ? p.w : 0.f;
    return p;
}

// ---------------------------------------------------------------------------
// Kernel 1: grid-wide softmax pass. One wave per 8-row chunk; writes
// p[0..511] (zeros beyond kl inside written groups) + pb at [512] per row.
// Identical math to the fused kernel's producer waves.
// ---------------------------------------------------------------------------
__global__ __launch_bounds__(64 * SMC)
void ForwardSumLoss_77378130805413_softmax(const float* __restrict__ attn,
                                           const int* __restrict__ in_lens,
                                           const int* __restrict__ out_lens,
                                           float* __restrict__ ws)
{
    const int b    = blockIdx.x;
    const int wave = threadIdx.x >> 6;
    const int lane = threadIdx.x & 63;

    int kl = in_lens[b];  kl = kl < 1 ? 1 : (kl > TKK ? TKK : kl);
    int ql = out_lens[b]; ql = ql < 1 ? 1 : (ql > TQQ ? TQQ : ql);

    const int t0 = (blockIdx.y * SMC + wave) * CR;
    if (t0 >= ql) return;

    const float* base = attn + (size_t)b * TQQ * TKK;
    const int j0 = 8 * lane;

    float4 x0[CR], x1[CR];
    #pragma unroll
    for (int r = 0; r < CR; ++r) {
        x0[r] = make_float4(-1e30f, -1e30f, -1e30f, -1e30f);
        x1[r] = x0[r];
        const int t = t0 + r;
        if (t < ql) {
            const float* row = base + (size_t)t * TKK;
            if (j0 < kl)     x0[r] = *(const float4*)(row + j0);
            if (j0 + 4 < kl) x1[r] = *(const float4*)(row + j0 + 4);
        }
    }
    #pragma unroll
    for (int r = 0; r < CR; ++r) {
        const int t = t0 + r;
        if (t >= ql) continue;
        float va[8] = {x0[r].x, x0[r].y, x0[r].z, x0[r].w,
                       x1[r].x, x1[r].y, x1[r].z, x1[r].w};
        float m = -1.0f;  // blank logprob
        #pragma unroll
        for (int cc = 0; cc < 8; ++cc) if (j0 + cc < kl) m = fmaxf(m, va[cc]);
        m = wred_max(m);
        float pv[8]; float vsum = 0.f;
        #pragma unroll
        for (int cc = 0; cc < 8; ++cc) {
            pv[cc] = (j0 + cc < kl) ? __expf(va[cc] - m) : 0.f;
            vsum += pv[cc];
        }
        vsum = wred_sum(vsum);
        float vb   = __expf(-1.0f - m);
        float rinv = 1.0f / (vsum + vb);
        float* wrow = ws + ((size_t)b * TQQ + t) * WSROW;
        if (j0 < kl) {
            *(float4*)(wrow + j0)     = make_float4(pv[0]*rinv, pv[1]*rinv, pv[2]*rinv, pv[3]*rinv);
            *(float4*)(wrow + j0 + 4) = make_float4(pv[4]*rinv, pv[5]*rinv, pv[6]*rinv, pv[7]*rinv);
        }
        if (lane == 0) wrow[512] = vb * rinv;
    }
}

// ---------------------------------------------------------------------------
// Kernel 2: DP pass. 2 waves per block (one block per batch), register
// prefetch of 4 chunks from the L3-hot workspace. Wave0/wave1 recurrence,
// boundary ring and exponent protocol ported verbatim from the fused kernel.
// ---------------------------------------------------------------------------
struct CK { float4 P[CR]; float PB[CR]; };   // 40 VGPRs; static indexing only

__device__ __forceinline__ void pf_chunk(CK& c, const float* __restrict__ wsb,
                                         int k, int nchunks, int ql,
                                         int base4, int kl) {
    if (k >= nchunks) return;
    const int t0 = k * CR;
    #pragma unroll
    for (int r = 0; r < CR; ++r) {
        int t  = t0 + r;
        int tc = t < ql ? t : (ql - 1);        // clamp: rows >= ql unwritten
        const float* rp = wsb + (size_t)tc * WSROW;
        c.P[r]  = selp4(*(const float4*)(rp + base4), base4, kl);
        c.PB[r] = rp[512];
    }
}

__global__ __launch_bounds__(128, 1)
void ForwardSumLoss_77378130805413_dp(const float* __restrict__ ws,
                                      const int* __restrict__ in_lens,
                                      const int* __restrict__ out_lens,
                                      float* __restrict__ out)
{
    __shared__ float s_dumpE[513];
    __shared__ float s_dumpO[512];
    __shared__ float s_bring[BRN];            // boundary O[255](t) ring, wave0 scale
    __shared__ int   s_ef0[4];                // wave0 per-chunk exponent ring
    __shared__ int   s_w0, s_w1;
    __shared__ int   s_e0c, s_e1c;

    const int b    = blockIdx.x;
    const int tid  = threadIdx.x;
    const int wave = tid >> 6;
    const int lane = tid & 63;

    int kl = in_lens[b];  kl = kl < 1 ? 1 : (kl > TKK ? TKK : kl);
    int ql = out_lens[b]; ql = ql < 1 ? 1 : (ql > TQQ ? TQQ : ql);
    const int nchunks = (ql + CR - 1) / CR;

    if (tid < BRN) s_bring[tid] = 0.f;
    if (tid == 32) s_w0 = -1;
    if (tid == 33) s_w1 = -1;
    __syncthreads();

    volatile int* vw0  = &s_w0;
    volatile int* vw1  = &s_w1;
    volatile int* vEF0 = s_ef0;

    const float T = 1.0995116e12f;   // 2^40
    const float* wsb = ws + (size_t)b * TQQ * WSROW;

    if (wave == 0) {
        // ------------- DP wave 0: state pairs m = 0..255 -------------
        float E[4] = {0,0,0,0}, O[4] = {0,0,0,0};
        int e0c = 0;
        const int base4 = 4 * lane;
        int w1s = -9;
        int k = 0;

        CK c0, c1, c2, c3;
        pf_chunk(c0, wsb, 0, nchunks, ql, base4, kl);
        pf_chunk(c1, wsb, 1, nchunks, ql, base4, kl);
        pf_chunk(c2, wsb, 2, nchunks, ql, base4, kl);
        pf_chunk(c3, wsb, 3, nchunks, ql, base4, kl);

        auto body = [&](CK& c) {
            const int t0   = k * CR;
            const int rows = min(ql - t0, CR);
            if (k >= 2) { while (w1s < k - 2) { w1s = *vw1; } }   // bring-ring capacity
            asm volatile("" ::: "memory");
            if (rows == CR) {
                #pragma unroll
                for (int r = 0; r < CR; ++r) {
                    if (k == 0 && r == 0) {
                        E[0] = (lane == 0) ? c.PB[0]  * T : 0.f;
                        O[0] = (lane == 0) ? c.P[0].x * T : 0.f;
                    } else {
                        float o_prev = dpp_wave_shr1(O[3], 0.0f);
                        step_quad(c.P[r], c.PB[r], o_prev, E, O);
                    }
                    if (r < CR - 1) { if (lane == 63) s_bring[(t0 + r) & (BRN - 1)] = O[3]; }
                }
                float m0 = fmaxf(fmaxf(fmaxf(E[0], E[1]), fmaxf(E[2], E[3])),
                                 fmaxf(fmaxf(O[0], O[1]), fmaxf(O[2], O[3])));
                m0 = wred_max(m0);
                int ef = 0;
                if (m0 > 0.f) ef = 167 - (int)((__float_as_uint(m0) >> 23) & 255);
                float fh = pow2i(ef - (ef >> 1));
                float fl = pow2i(ef >> 1);
                #pragma unroll
                for (int i = 0; i < 4; ++i) { E[i] = (E[i] * fh) * fl; O[i] = (O[i] * fh) * fl; }
                e0c += ef;
                if (lane == 0) vEF0[k & 3] = ef;
                if (lane == 63) s_bring[(t0 + CR - 1) & (BRN - 1)] = O[3];  // post-rescale
            } else {
                #pragma unroll
                for (int r = 0; r < CR; ++r) {
                    if (r < rows) {
                        if (k == 0 && r == 0) {
                            E[0] = (lane == 0) ? c.PB[0]  * T : 0.f;
                            O[0] = (lane == 0) ? c.P[0].x * T : 0.f;
                        } else {
                            float o_prev = dpp_wave_shr1(O[3], 0.0f);
                            step_quad(c.P[r], c.PB[r], o_prev, E, O);
                        }
                        if (lane == 63) s_bring[(t0 + r) & (BRN - 1)] = O[3];
                    }
                }
            }
            asm volatile("" ::: "memory");
            if (lane == 0) *vw0 = k;
            pf_chunk(c, wsb, k + 4, nchunks, ql, base4, kl);
            w1s = *vw1;                       // early probe for next gate
        };

        while (k < nchunks) {
            body(c0); if (++k >= nchunks) break;
            body(c1); if (++k >= nchunks) break;
            body(c2); if (++k >= nchunks) break;
            body(c3); ++k;
        }
        #pragma unroll
        for (int i = 0; i < 4; ++i) {
            s_dumpE[base4 + i] = E[i];
            s_dumpO[base4 + i] = O[i];
        }
        if (lane == 0) s_e0c = e0c;
    } else if (wave == 1) {
        // ------------- DP wave 1: pairs m = 256..511 + top blank (e512) -------------
        float E[4] = {0,0,0,0}, O[4] = {0,0,0,0}, e512 = 0.f;
        int e0c = 0, e1c = 0;
        const int base4 = 256 + 4 * lane;
        int w0s = -9;
        int k = 0;

        CK c0, c1, c2, c3;
        pf_chunk(c0, wsb, 0, nchunks, ql, base4, kl);
        pf_chunk(c1, wsb, 1, nchunks, ql, base4, kl);
        pf_chunk(c2, wsb, 2, nchunks, ql, base4, kl);
        pf_chunk(c3, wsb, 3, nchunks, ql, base4, kl);

        auto body = [&](CK& c) {
            const int t0   = k * CR;
            const int rows = min(ql - t0, CR);
            while (w0s < k) { w0s = *vw0; }
            asm volatile("" ::: "memory");

            // boundary conversion factor 2^(e1c - e0c), exact, two-stage
            int dE = e1c - e0c;
            dE = dE < -250 ? -250 : (dE > 250 ? 250 : dE);
            const float Ch = pow2i(dE - (dE >> 1));
            const float Cl = pow2i(dE >> 1);

            if (rows == CR) {
                float BND[CR];
                #pragma unroll
                for (int r = 0; r < CR; ++r)
                    BND[r] = (s_bring[(t0 - 1 + r) & (BRN - 1)] * Ch) * Cl;
                #pragma unroll
                for (int r = 0; r < CR; ++r) {
                    float o_prev = dpp_wave_shr1(O[3], 0.0f);
                    o_prev = (lane == 0) ? BND[r] : o_prev;
                    float te = e512 + O[3]; e512 = te * c.PB[r];   // old O[3] (lane63 = m511)
                    step_quad(c.P[r], c.PB[r], o_prev, E, O);
                }
                float m1 = fmaxf(fmaxf(fmaxf(E[0], E[1]), fmaxf(E[2], E[3])),
                                 fmaxf(fmaxf(O[0], O[1]), fmaxf(O[2], O[3])));
                m1 = fmaxf(m1, e512);
                m1 = wred_max(m1);
                int ef0k = vEF0[k & 3];     // published before vw0 = k
                int ef1  = (m1 > 0.f) ? (167 - (int)((__float_as_uint(m1) >> 23) & 255))
                                      : ef0k;   // no mass: track wave0, freeze delta
                float fh = pow2i(ef1 - (ef1 >> 1));
                float fl = pow2i(ef1 >> 1);
                #pragma unroll
                for (int i = 0; i < 4; ++i) { E[i] = (E[i] * fh) * fl; O[i] = (O[i] * fh) * fl; }
                e512 = (e512 * fh) * fl;
                e1c += ef1;
                e0c += ef0k;
            } else {
                #pragma unroll
                for (int r = 0; r < CR; ++r) {
                    if (r < rows) {
                        float bnd = (s_bring[(t0 - 1 + r) & (BRN - 1)] * Ch) * Cl;
                        float o_prev = dpp_wave_shr1(O[3], 0.0f);
                        o_prev = (lane == 0) ? bnd : o_prev;
                        float te = e512 + O[3]; e512 = te * c.PB[r];
                        step_quad(c.P[r], c.PB[r], o_prev, E, O);
                    }
                }
            }
            asm volatile("" ::: "memory");
            if (lane == 0) *vw1 = k;
            pf_chunk(c, wsb, k + 4, nchunks, ql, base4, kl);
            w0s = *vw0;                       // early probe for next gate
        };

        while (k < nchunks) {
            body(c0); if (++k >= nchunks) break;
            body(c1); if (++k >= nchunks) break;
            body(c2); if (++k >= nchunks) break;
            body(c3); ++k;
        }
        #pragma unroll
        for (int i = 0; i < 4; ++i) {
            s_dumpE[base4 + i] = E[i];
            s_dumpO[base4 + i] = O[i];
        }
        if (lane == 63) s_dumpE[512] = e512;
        if (lane == 0)  s_e1c = e1c;
    }

    __syncthreads();
    if (tid == 0) {
        const double logTd = 27.725887222397812;   // 40*ln2
        const double LN2d  = 0.69314718055994531;
        float aE = s_dumpE[kl];
        float aO = s_dumpO[kl - 1];
        int e0c = s_e0c, e1c = s_e1c;
        double sE = logTd + (double)((kl     >= 256) ? e1c : e0c) * LN2d;
        double sO = logTd + (double)((kl - 1 >= 256) ? e1c : e0c) * LN2d;
        double lE = (aE > 0.f) ? log((double)aE) - sE : -1e300;
        double lO = (aO > 0.f) ? log((double)aO) - sO : -1e300;
        double mx = fmax(lE, lO);
        double ll = (mx < -1e290) ? -745.0 : mx + log(exp(lE - mx) + exp(lO - mx));
        float val = (float)(-ll / ((double)kl * (double)BB));
        atomicAdd(out, val);
    }
}

// ---------------------------------------------------------------------------
// Fallback: original fused kernel (verbatim), used when workspace is too small
// ---------------------------------------------------------------------------
__global__ __launch_bounds__(NW * 64)
void ForwardSumLoss_77378130805413_kernel(const float* __restrict__ attn,
                                          const int* __restrict__ in_lens,
                                          const int* __restrict__ out_lens,
                                          float* __restrict__ out)
{
    __shared__ float s_slots[RS * CR * SLOT_F];   // 133120 B
    __shared__ float s_dumpE[513];
    __shared__ float s_dumpO[512];
    __shared__ float s_bring[BRN];
    __shared__ int   s_ef0[4];
    __shared__ int   s_ready[RS];
    __shared__ int   s_w0, s_w1;
    __shared__ int   s_e0c, s_e1c;

    const int b    = blockIdx.x;
    const int tid  = threadIdx.x;
    const int wave = tid >> 6;
    const int lane = tid & 63;

    int kl = in_lens[b];  kl = kl < 1 ? 1 : (kl > TKK ? TKK : kl);
    int ql = out_lens[b]; ql = ql < 1 ? 1 : (ql > TQQ ? TQQ : ql);
    const int nchunks = (ql + CR - 1) / CR;

    if (tid < RS)  s_ready[tid] = -1;
    if (tid < BRN) s_bring[tid] = 0.f;
    if (tid == 32) s_w0 = -1;
    if (tid == 33) s_w1 = -1;
    __syncthreads();

    volatile int* vready = s_ready;
    volatile int* vw0    = &s_w0;
    volatile int* vw1    = &s_w1;
    volatile int* vEF0   = s_ef0;

    const float T = 1.0995116e12f;   // 2^40

    if (wave == 0) {
        __builtin_amdgcn_s_setprio(3);
        float E[4] = {0,0,0,0}, O[4] = {0,0,0,0};
        int e0c = 0;
        const int base4 = 4 * lane;
        int rdyN = -9, w1s = -9;

        for (int k = 0; k < nchunks; ++k) {
            const int t0   = k * CR;
            const int rows = min(ql - t0, CR);
            if (k >= 2) { while (w1s < k - 2) { w1s = *vw1; } }
            if (rdyN != k) { while (vready[k & (RS - 1)] != k) {} }
            asm volatile("" ::: "memory");
            const float* bp = s_slots + (size_t)(k & (RS - 1)) * CR * SLOT_F;

            if (rows == CR) {
                float4 P[CR]; float PB[CR];
                #pragma unroll
                for (int r = 0; r < CR; ++r) {
                    P[r]  = *(const float4*)(bp + r * SLOT_F + base4);
                    PB[r] = bp[r * SLOT_F + 512];
                }
                rdyN = vready[(k + 1) & (RS - 1)];
                w1s  = *vw1;
                #pragma unroll
                for (int r = 0; r < CR; ++r) {
                    if (k == 0 && r == 0) {
                        E[0] = (lane == 0) ? PB[0]  * T : 0.f;
                        O[0] = (lane == 0) ? P[0].x * T : 0.f;
                    } else {
                        float o_prev = dpp_wave_shr1(O[3], 0.0f);
                        step_quad(P[r], PB[r], o_prev, E, O);
                    }
                    if (r < CR - 1) { if (lane == 63) s_bring[(t0 + r) & (BRN - 1)] = O[3]; }
                }
                float m0 = fmaxf(fmaxf(fmaxf(E[0], E[1]), fmaxf(E[2], E[3])),
                                 fmaxf(fmaxf(O[0], O[1]), fmaxf(O[2], O[3])));
                m0 = wred_max(m0);
                int ef = 0;
                if (m0 > 0.f) ef = 167 - (int)((__float_as_uint(m0) >> 23) & 255);
                float fh = pow2i(ef - (ef >> 1));
                float fl = pow2i(ef >> 1);
                #pragma unroll
                for (int i = 0; i < 4; ++i) { E[i] = (E[i] * fh) * fl; O[i] = (O[i] * fh) * fl; }
                e0c += ef;
                if (lane == 0) vEF0[k & 3] = ef;
                if (lane == 63) s_bring[(t0 + CR - 1) & (BRN - 1)] = O[3];
            } else {
                for (int r = 0; r < rows; ++r) {
                    const float* sq = bp + r * SLOT_F;
                    float4 p = *(const float4*)(sq + base4);
                    float pb = sq[512];
                    if (k == 0 && r == 0) {
                        E[0] = (lane == 0) ? pb  * T : 0.f;
                        O[0] = (lane == 0) ? p.x * T : 0.f;
                    } else {
                        float o_prev = dpp_wave_shr1(O[3], 0.0f);
                        step_quad(p, pb, o_prev, E, O);
                    }
                    if (lane == 63) s_bring[(t0 + r) & (BRN - 1)] = O[3];
                }
            }
            asm volatile("" ::: "memory");
            if (lane == 0) *vw0 = k;
        }
        #pragma unroll
        for (int i = 0; i < 4; ++i) {
            s_dumpE[base4 + i] = E[i];
            s_dumpO[base4 + i] = O[i];
        }
        if (lane == 0) s_e0c = e0c;
    } else if (wave == 1) {
        __builtin_amdgcn_s_setprio(3);
        float E[4] = {0,0,0,0}, O[4] = {0,0,0,0}, e512 = 0.f;
        int e0c = 0, e1c = 0;
        const int base4 = 256 + 4 * lane;
        int w0s = -9;

        for (int k = 0; k < nchunks; ++k) {
            const int t0   = k * CR;
            const int rows = min(ql - t0, CR);
            while (w0s < k) { w0s = *vw0; }
            asm volatile("" ::: "memory");
            const float* bp = s_slots + (size_t)(k & (RS - 1)) * CR * SLOT_F;

            int dE = e1c - e0c;
            dE = dE < -250 ? -250 : (dE > 250 ? 250 : dE);
            const float Ch = pow2i(dE - (dE >> 1));
            const float Cl = pow2i(dE >> 1);

            if (rows == CR) {
                float4 P[CR]; float PB[CR], BND[CR];
                #pragma unroll
                for (int r = 0; r < CR; ++r) {
                    P[r]   = *(const float4*)(bp + r * SLOT_F + base4);
                    PB[r]  = bp[r * SLOT_F + 512];
                    BND[r] = (s_bring[(t0 - 1 + r) & (BRN - 1)] * Ch) * Cl;
                }
                w0s = *vw0;
                #pragma unroll
                for (int r = 0; r < CR; ++r) {
                    float o_prev = dpp_wave_shr1(O[3], 0.0f);
                    o_prev = (lane == 0) ? BND[r] : o_prev;
                    float te = e512 + O[3]; e512 = te * PB[r];
                    step_quad(P[r], PB[r], o_prev, E, O);
                }
                float m1 = fmaxf(fmaxf(fmaxf(E[0], E[1]), fmaxf(E[2], E[3])),
                                 fmaxf(fmaxf(O[0], O[1]), fmaxf(O[2], O[3])));
                m1 = fmaxf(m1, e512);
                m1 = wred_max(m1);
                int ef0k = vEF0[k & 3];
                int ef1  = (m1 > 0.f) ? (167 - (int)((__float_as_uint(m1) >> 23) & 255))
                                      : ef0k;
                float fh = pow2i(ef1 - (ef1 >> 1));
                float fl = pow2i(ef1 >> 1);
                #pragma unroll
                for (int i = 0; i < 4; ++i) { E[i] = (E[i] * fh) * fl; O[i] = (O[i] * fh) * fl; }
                e512 = (e512 * fh) * fl;
                e1c += ef1;
                e0c += ef0k;
            } else {
                for (int r = 0; r < rows; ++r) {
                    const float* sq = bp + r * SLOT_F;
                    float4 p = *(const float4*)(sq + base4);
                    float pb = sq[512];
                    float bnd = (s_bring[(t0 - 1 + r) & (BRN - 1)] * Ch) * Cl;
                    float o_prev = dpp_wave_shr1(O[3], 0.0f);
                    o_prev = (lane == 0) ? bnd : o_prev;
                    float te = e512 + O[3]; e512 = te * pb;
                    step_quad(p, pb, o_prev, E, O);
                }
            }
            asm volatile("" ::: "memory");
            if (lane == 0) *vw1 = k;
        }
        #pragma unroll
        for (int i = 0; i < 4; ++i) {
            s_dumpE[base4 + i] = E[i];
            s_dumpO[base4 + i] = O[i];
        }
        if (lane == 63) s_dumpE[512] = e512;
        if (lane == 0)  s_e1c = e1c;
    } else {
        const int pidx = wave - 2;
        const float* base = attn + (size_t)b * TQQ * TKK;
        const int j0 = 8 * lane;

        for (int c = pidx; c < nchunks; c += NW - 2) {
            const int t0 = c * CR;
            while (*vw1 < c - RS) { __builtin_amdgcn_s_sleep(4); }
            asm volatile("" ::: "memory");

            float4 x0[CR], x1[CR];
            #pragma unroll
            for (int r = 0; r < CR; ++r) {
                x0[r] = make_float4(-1e30f, -1e30f, -1e30f, -1e30f);
                x1[r] = x0[r];
                const int t = t0 + r;
                if (t < ql) {
                    const float* row = base + (size_t)t * TKK;
                    if (j0 < kl)     x0[r] = *(const float4*)(row + j0);
                    if (j0 + 4 < kl) x1[r] = *(const float4*)(row + j0 + 4);
                }
            }
            float* bp = s_slots + (size_t)(c & (RS - 1)) * CR * SLOT_F;
            #pragma unroll
            for (int r = 0; r < CR; ++r) {
                const int t = t0 + r;
                if (t >= ql) continue;
                float va[8] = {x0[r].x, x0[r].y, x0[r].z, x0[r].w,
                               x1[r].x, x1[r].y, x1[r].z, x1[r].w};
                float m = -1.0f;
                #pragma unroll
                for (int cc = 0; cc < 8; ++cc) if (j0 + cc < kl) m = fmaxf(m, va[cc]);
                m = wred_max(m);
                float pv[8]; float vsum = 0.f;
                #pragma unroll
                for (int cc = 0; cc < 8; ++cc) {
                    pv[cc] = (j0 + cc < kl) ? __expf(va[cc] - m) : 0.f;
                    vsum += pv[cc];
                }
                vsum = wred_sum(vsum);
                float vb   = __expf(-1.0f - m);
                float rinv = 1.0f / (vsum + vb);
                float* sp = bp + (size_t)r * SLOT_F;
                *(float4*)(sp + j0)     = make_float4(pv[0]*rinv, pv[1]*rinv, pv[2]*rinv, pv[3]*rinv);
                *(float4*)(sp + j0 + 4) = make_float4(pv[4]*rinv, pv[5]*rinv, pv[6]*rinv, pv[7]*rinv);
                if (lane == 0) sp[512] = vb * rinv;
            }
            __threadfence_block();
            if (lane == 0) vready[c & (RS - 1)] = c;
        }
    }

    __syncthreads();
    if (tid == 0) {
        const double logTd = 27.725887222397812;
        const double LN2d  = 0.69314718055994531;
        float aE = s_dumpE[kl];
        float aO = s_dumpO[kl - 1];
        int e0c = s_e0c, e1c = s_e1c;
        double sE = logTd + (double)((kl     >= 256) ? e1c : e0c) * LN2d;
        double sO = logTd + (double)((kl - 1 >= 256) ? e1c : e0c) * LN2d;
        double lE = (aE > 0.f) ? log((double)aE) - sE : -1e300;
        double lO = (aO > 0.f) ? log((double)aO) - sO : -1e300;
        double mx = fmax(lE, lO);
        double ll = (mx < -1e290) ? -745.0 : mx + log(exp(lE - mx) + exp(lO - mx));
        float val = (float)(-ll / ((double)kl * (double)BB));
        atomicAdd(out, val);
    }
}

extern "C" void kernel_launch(void* const* d_in, const int* in_sizes, int n_in,
                              void* d_out, int out_size, void* d_ws, size_t ws_size,
                              hipStream_t stream) {
    const float* attn     = (const float*)d_in[0];
    const int*   in_lens  = (const int*)d_in[1];
    const int*   out_lens = (const int*)d_in[2];
    float* out = (float*)d_out;
    hipMemsetAsync(out, 0, sizeof(float), stream);

    const size_t need = (size_t)BB * TQQ * WSROW * sizeof(float);   // ~127 MB
    if (d_ws != nullptr && ws_size >= need) {
        float* ws = (float*)d_ws;
        dim3 g1(BB, (TQQ + SMC * CR - 1) / (SMC * CR));   // 32 x 63
        hipLaunchKernelGGL(ForwardSumLoss_77378130805413_softmax,
                           g1, dim3(64 * SMC), 0, stream,
                           attn, in_lens, out_lens, ws);
        hipLaunchKernelGGL(ForwardSumLoss_77378130805413_dp,
                           dim3(BB), dim3(128), 0, stream,
                           (const float*)ws, in_lens, out_lens, out);
    } else {
        hipLaunchKernelGGL(ForwardSumLoss_77378130805413_kernel,
                           dim3(BB), dim3(NW * 64), 0, stream,
                           attn, in_lens, out_lens, out);
    }
}

// Round 2
// 415.263 us; speedup vs baseline: 1.2548x; 1.2548x over previous
//
#include <hip/hip_runtime.h>
#include <math.h>

#define BB 32
#define TQQ 2000
#define TKK 512
#define CR 8            // rows (time steps) per chunk
#define RS 8            // ring slots, in chunks
#define NW 8            // 2 consumer waves + 6 producer (copy) waves
#define SLOT_F 520      // fused fallback: floats per row slot
#define LROW 512        // two-pass: floats per row (p only, pb separate)
#define BRN 32          // boundary ring entries (4 chunks)
#define SMC 4           // softmax kernel: waves per block

__device__ __forceinline__ float dpp_mv_111(float x, float old) {
    return __int_as_float(__builtin_amdgcn_update_dpp(__float_as_int(old), __float_as_int(x), 0x111, 0xf, 0xf, false));
}
__device__ __forceinline__ float dpp_mv_112(float x, float old) {
    return __int_as_float(__builtin_amdgcn_update_dpp(__float_as_int(old), __float_as_int(x), 0x112, 0xf, 0xf, false));
}
__device__ __forceinline__ float dpp_mv_114(float x, float old) {
    return __int_as_float(__builtin_amdgcn_update_dpp(__float_as_int(old), __float_as_int(x), 0x114, 0xf, 0xf, false));
}
__device__ __forceinline__ float dpp_mv_118(float x, float old) {
    return __int_as_float(__builtin_amdgcn_update_dpp(__float_as_int(old), __float_as_int(x), 0x118, 0xf, 0xf, false));
}
__device__ __forceinline__ float dpp_mv_b15(float x, float old) {
    return __int_as_float(__builtin_amdgcn_update_dpp(__float_as_int(old), __float_as_int(x), 0x142, 0xf, 0xf, false));
}
__device__ __forceinline__ float dpp_mv_b31(float x, float old) {
    return __int_as_float(__builtin_amdgcn_update_dpp(__float_as_int(old), __float_as_int(x), 0x143, 0xf, 0xf, false));
}
__device__ __forceinline__ float dpp_wave_shr1(float x, float old) {
    return __int_as_float(__builtin_amdgcn_update_dpp(__float_as_int(old), __float_as_int(x), 0x138, 0xf, 0xf, false));
}

__device__ __forceinline__ float wred_max(float x) {
    x = fmaxf(x, dpp_mv_111(x, -1e38f));
    x = fmaxf(x, dpp_mv_112(x, -1e38f));
    x = fmaxf(x, dpp_mv_114(x, -1e38f));
    x = fmaxf(x, dpp_mv_118(x, -1e38f));
    x = fmaxf(x, dpp_mv_b15(x, -1e38f));
    x = fmaxf(x, dpp_mv_b31(x, -1e38f));
    return __int_as_float(__builtin_amdgcn_readlane(__float_as_int(x), 63));
}
__device__ __forceinline__ float wred_sum(float x) {
    x += dpp_mv_111(x, 0.0f);
    x += dpp_mv_112(x, 0.0f);
    x += dpp_mv_114(x, 0.0f);
    x += dpp_mv_118(x, 0.0f);
    x += dpp_mv_b15(x, 0.0f);
    x += dpp_mv_b31(x, 0.0f);
    return __int_as_float(__builtin_amdgcn_readlane(__float_as_int(x), 63));
}

__device__ __forceinline__ float pow2i(int e) {    // e in [-126, 127]
    return __int_as_float((unsigned)(e + 127) << 23);
}

// one DP step over 4 state-pairs/lane; uses OLD O[i-1] (descending order)
__device__ __forceinline__ void step_quad(float4 p, float pb, float o_prev,
                                          float E[4], float O[4]) {
    float t3 = E[3] + O[2];  O[3] = (O[3] + t3) * p.w;  E[3] = t3 * pb;
    float t2 = E[2] + O[1];  O[2] = (O[2] + t2) * p.z;  E[2] = t2 * pb;
    float t1 = E[1] + O[0];  O[1] = (O[1] + t1) * p.y;  E[1] = t1 * pb;
    float t0 = E[0] + o_prev; O[0] = (O[0] + t0) * p.x; E[0] = t0 * pb;
}

// global -> LDS DMA (per-lane global src; LDS dest = uniform base + lane*size)
__device__ __forceinline__ void gl_lds16(const float* g, float* l) {
    __builtin_amdgcn_global_load_lds(
        (const __attribute__((address_space(1))) unsigned int*)g,
        (__attribute__((address_space(3))) unsigned int*)l, 16, 0, 0);
}
__device__ __forceinline__ void gl_lds4(const float* g, float* l) {
    __builtin_amdgcn_global_load_lds(
        (const __attribute__((address_space(1))) unsigned int*)g,
        (__attribute__((address_space(3))) unsigned int*)l, 4, 0, 0);
}

// ---------------------------------------------------------------------------
// Kernel 1: grid-wide softmax pass.
// ws layout: p rows [b][t][512] (stride 512 f32, 2048B-aligned rows), then
// pb array [b][t] at offset BB*TQQ*512. Only floats [0, 8*ceil(kl/8)) of each
// p-row are written; the dp kernel never reads past 4*ceil(kl/4).
// ---------------------------------------------------------------------------
__global__ __launch_bounds__(64 * SMC)
void ForwardSumLoss_77378130805413_softmax(const float* __restrict__ attn,
                                           const int* __restrict__ in_lens,
                                           const int* __restrict__ out_lens,
                                           float* __restrict__ ws)
{
    const int b    = blockIdx.x;
    const int wave = threadIdx.x >> 6;
    const int lane = threadIdx.x & 63;

    int kl = in_lens[b];  kl = kl < 1 ? 1 : (kl > TKK ? TKK : kl);
    int ql = out_lens[b]; ql = ql < 1 ? 1 : (ql > TQQ ? TQQ : ql);

    const int t0 = (blockIdx.y * SMC + wave) * CR;
    if (t0 >= ql) return;

    const float* base = attn + (size_t)b * TQQ * TKK;
    float* wsp  = ws;
    float* wspb = ws + (size_t)BB * TQQ * LROW;
    const int j0 = 8 * lane;

    float4 x0[CR], x1[CR];
    #pragma unroll
    for (int r = 0; r < CR; ++r) {
        x0[r] = make_float4(-1e30f, -1e30f, -1e30f, -1e30f);
        x1[r] = x0[r];
        const int t = t0 + r;
        if (t < ql) {
            const float* row = base + (size_t)t * TKK;
            if (j0 < kl)     x0[r] = *(const float4*)(row + j0);
            if (j0 + 4 < kl) x1[r] = *(const float4*)(row + j0 + 4);
        }
    }
    #pragma unroll
    for (int r = 0; r < CR; ++r) {
        const int t = t0 + r;
        if (t >= ql) continue;
        float va[8] = {x0[r].x, x0[r].y, x0[r].z, x0[r].w,
                       x1[r].x, x1[r].y, x1[r].z, x1[r].w};
        float m = -1.0f;  // blank logprob
        #pragma unroll
        for (int cc = 0; cc < 8; ++cc) if (j0 + cc < kl) m = fmaxf(m, va[cc]);
        m = wred_max(m);
        float pv[8]; float vsum = 0.f;
        #pragma unroll
        for (int cc = 0; cc < 8; ++cc) {
            pv[cc] = (j0 + cc < kl) ? __expf(va[cc] - m) : 0.f;
            vsum += pv[cc];
        }
        vsum = wred_sum(vsum);
        float vb   = __expf(-1.0f - m);
        float rinv = 1.0f / (vsum + vb);
        float* wrow = wsp + ((size_t)b * TQQ + t) * LROW;
        if (j0 < kl) {   // writes [j0, j0+8): zeros beyond kl inside the block
            *(float4*)(wrow + j0)     = make_float4(pv[0]*rinv, pv[1]*rinv, pv[2]*rinv, pv[3]*rinv);
            *(float4*)(wrow + j0 + 4) = make_float4(pv[4]*rinv, pv[5]*rinv, pv[6]*rinv, pv[7]*rinv);
        }
        if (lane == 0) wspb[(size_t)b * TQQ + t] = vb * rinv;
    }
}

// ---------------------------------------------------------------------------
// Kernel 2: DP pass, structurally identical to the proven fused kernel:
// 2 DP waves reading LDS (88-VGPR regime, debugged handshake verbatim) +
// 6 producer waves that are now pure global_load_lds DMA copies of the
// precomputed workspace (only ceil(kl*4/16) bytes per row; the remainder of
// each LDS row is zeroed once at start and never overwritten).
// ---------------------------------------------------------------------------
__global__ __launch_bounds__(NW * 64)
void ForwardSumLoss_77378130805413_dp(const float* __restrict__ ws,
                                      const int* __restrict__ in_lens,
                                      const int* __restrict__ out_lens,
                                      float* __restrict__ out)
{
    __shared__ float s_slots[RS * CR * LROW];     // 131072 B
    __shared__ float s_pb[RS * CR];
    __shared__ float s_dumpE[513];
    __shared__ float s_dumpO[512];
    __shared__ float s_bring[BRN];
    __shared__ int   s_ef0[4];
    __shared__ int   s_ready[RS];
    __shared__ int   s_w0, s_w1;
    __shared__ int   s_e0c, s_e1c;

    const int b    = blockIdx.x;
    const int tid  = threadIdx.x;
    const int wave = tid >> 6;
    const int lane = tid & 63;

    int kl = in_lens[b];  kl = kl < 1 ? 1 : (kl > TKK ? TKK : kl);
    int ql = out_lens[b]; ql = ql < 1 ? 1 : (ql > TQQ ? TQQ : ql);
    const int nchunks = (ql + CR - 1) / CR;

    // zero all p slots once: lanes beyond kl then read exact zeros forever,
    // since producers only ever overwrite the first ceil(kl*4/16) bytes/row.
    {
        float4 z4 = make_float4(0.f, 0.f, 0.f, 0.f);
        float4* s4 = (float4*)s_slots;
        #pragma unroll 4
        for (int i = tid; i < RS * CR * (LROW / 4); i += NW * 64) s4[i] = z4;
    }
    if (tid < RS * CR) s_pb[tid] = 0.f;
    if (tid < RS)  s_ready[tid] = -1;
    if (tid < BRN) s_bring[tid] = 0.f;
    if (tid == 32) s_w0 = -1;
    if (tid == 33) s_w1 = -1;
    __syncthreads();

    volatile int* vready = s_ready;
    volatile int* vw0    = &s_w0;
    volatile int* vw1    = &s_w1;
    volatile int* vEF0   = s_ef0;

    const float T = 1.0995116e12f;   // 2^40

    if (wave == 0) {
        // ------------- DP wave 0: state pairs m = 0..255 -------------
        __builtin_amdgcn_s_setprio(3);
        float E[4] = {0,0,0,0}, O[4] = {0,0,0,0};
        int e0c = 0;
        const int base4 = 4 * lane;
        int rdyN = -9, w1s = -9;

        for (int k = 0; k < nchunks; ++k) {
            const int t0   = k * CR;
            const int rows = min(ql - t0, CR);
            if (k >= 2) { while (w1s < k - 2) { w1s = *vw1; } }     // bring-ring capacity
            if (rdyN != k) { while (vready[k & (RS - 1)] != k) {} }
            asm volatile("" ::: "memory");
            const float* bp = s_slots + (size_t)(k & (RS - 1)) * CR * LROW;
            const float* pbs = s_pb + (k & (RS - 1)) * CR;

            if (rows == CR) {
                float4 P[CR]; float PB[CR];
                #pragma unroll
                for (int r = 0; r < CR; ++r) {
                    P[r]  = *(const float4*)(bp + r * LROW + base4);
                    PB[r] = pbs[r];
                }
                rdyN = vready[(k + 1) & (RS - 1)];   // early probes
                w1s  = *vw1;
                #pragma unroll
                for (int r = 0; r < CR; ++r) {
                    if (k == 0 && r == 0) {
                        E[0] = (lane == 0) ? PB[0]  * T : 0.f;
                        O[0] = (lane == 0) ? P[0].x * T : 0.f;
                    } else {
                        float o_prev = dpp_wave_shr1(O[3], 0.0f);
                        step_quad(P[r], PB[r], o_prev, E, O);
                    }
                    if (r < CR - 1) { if (lane == 63) s_bring[(t0 + r) & (BRN - 1)] = O[3]; }
                }
                float m0 = fmaxf(fmaxf(fmaxf(E[0], E[1]), fmaxf(E[2], E[3])),
                                 fmaxf(fmaxf(O[0], O[1]), fmaxf(O[2], O[3])));
                m0 = wred_max(m0);
                int ef = 0;
                if (m0 > 0.f) ef = 167 - (int)((__float_as_uint(m0) >> 23) & 255);
                float fh = pow2i(ef - (ef >> 1));
                float fl = pow2i(ef >> 1);
                #pragma unroll
                for (int i = 0; i < 4; ++i) { E[i] = (E[i] * fh) * fl; O[i] = (O[i] * fh) * fl; }
                e0c += ef;
                if (lane == 0) vEF0[k & 3] = ef;
                if (lane == 63) s_bring[(t0 + CR - 1) & (BRN - 1)] = O[3];  // post-rescale
            } else {
                for (int r = 0; r < rows; ++r) {
                    const float* sq = bp + r * LROW;
                    float4 p = *(const float4*)(sq + base4);
                    float pb = pbs[r];
                    if (k == 0 && r == 0) {
                        E[0] = (lane == 0) ? pb  * T : 0.f;
                        O[0] = (lane == 0) ? p.x * T : 0.f;
                    } else {
                        float o_prev = dpp_wave_shr1(O[3], 0.0f);
                        step_quad(p, pb, o_prev, E, O);
                    }
                    if (lane == 63) s_bring[(t0 + r) & (BRN - 1)] = O[3];
                }
            }
            asm volatile("" ::: "memory");
            if (lane == 0) *vw0 = k;
        }
        #pragma unroll
        for (int i = 0; i < 4; ++i) {
            s_dumpE[base4 + i] = E[i];
            s_dumpO[base4 + i] = O[i];
        }
        if (lane == 0) s_e0c = e0c;
    } else if (wave == 1) {
        // ------------- DP wave 1: pairs m = 256..511 + top blank (e512) -------------
        __builtin_amdgcn_s_setprio(3);
        float E[4] = {0,0,0,0}, O[4] = {0,0,0,0}, e512 = 0.f;
        int e0c = 0, e1c = 0;
        const int base4 = 256 + 4 * lane;
        int w0s = -9;

        for (int k = 0; k < nchunks; ++k) {
            const int t0   = k * CR;
            const int rows = min(ql - t0, CR);
            while (w0s < k) { w0s = *vw0; }
            asm volatile("" ::: "memory");
            const float* bp = s_slots + (size_t)(k & (RS - 1)) * CR * LROW;
            const float* pbs = s_pb + (k & (RS - 1)) * CR;

            // boundary conversion factor 2^(e1c - e0c), exact, two-stage
            int dE = e1c - e0c;
            dE = dE < -250 ? -250 : (dE > 250 ? 250 : dE);
            const float Ch = pow2i(dE - (dE >> 1));
            const float Cl = pow2i(dE >> 1);

            if (rows == CR) {
                float4 P[CR]; float PB[CR], BND[CR];
                #pragma unroll
                for (int r = 0; r < CR; ++r) {
                    P[r]   = *(const float4*)(bp + r * LROW + base4);
                    PB[r]  = pbs[r];
                    BND[r] = (s_bring[(t0 - 1 + r) & (BRN - 1)] * Ch) * Cl;
                }
                w0s = *vw0;                 // early probe
                #pragma unroll
                for (int r = 0; r < CR; ++r) {
                    float o_prev = dpp_wave_shr1(O[3], 0.0f);
                    o_prev = (lane == 0) ? BND[r] : o_prev;
                    float te = e512 + O[3]; e512 = te * PB[r];   // old O[3] (lane63 = m511)
                    step_quad(P[r], PB[r], o_prev, E, O);
                }
                float m1 = fmaxf(fmaxf(fmaxf(E[0], E[1]), fmaxf(E[2], E[3])),
                                 fmaxf(fmaxf(O[0], O[1]), fmaxf(O[2], O[3])));
                m1 = fmaxf(m1, e512);
                m1 = wred_max(m1);
                int ef0k = vEF0[k & 3];     // published before vw0 = k
                int ef1  = (m1 > 0.f) ? (167 - (int)((__float_as_uint(m1) >> 23) & 255))
                                      : ef0k;   // no mass: track wave0, freeze delta
                float fh = pow2i(ef1 - (ef1 >> 1));
                float fl = pow2i(ef1 >> 1);
                #pragma unroll
                for (int i = 0; i < 4; ++i) { E[i] = (E[i] * fh) * fl; O[i] = (O[i] * fh) * fl; }
                e512 = (e512 * fh) * fl;
                e1c += ef1;
                e0c += ef0k;
            } else {
                for (int r = 0; r < rows; ++r) {
                    const float* sq = bp + r * LROW;
                    float4 p = *(const float4*)(sq + base4);
                    float pb = pbs[r];
                    float bnd = (s_bring[(t0 - 1 + r) & (BRN - 1)] * Ch) * Cl;
                    float o_prev = dpp_wave_shr1(O[3], 0.0f);
                    o_prev = (lane == 0) ? bnd : o_prev;
                    float te = e512 + O[3]; e512 = te * pb;
                    step_quad(p, pb, o_prev, E, O);
                }
            }
            asm volatile("" ::: "memory");
            if (lane == 0) *vw1 = k;
        }
        #pragma unroll
        for (int i = 0; i < 4; ++i) {
            s_dumpE[base4 + i] = E[i];
            s_dumpO[base4 + i] = O[i];
        }
        if (lane == 63) s_dumpE[512] = e512;
        if (lane == 0)  s_e1c = e1c;
    } else {
        // ------------- producer waves (6): pure DMA copy ws -> LDS -------------
        const int pidx = wave - 2;                  // 0..5
        const float* wp  = ws + (size_t)b * TQQ * LROW;
        const float* wpb = ws + (size_t)BB * TQQ * LROW + (size_t)b * TQQ;
        const int rowbytes = (kl * 4 + 15) & ~15;   // p bytes the DP waves consume
        const int half2 = rowbytes > 1024;

        for (int c = pidx; c < nchunks; c += NW - 2) {
            const int t0   = c * CR;
            const int rows = min(ql - t0, CR);
            while (*vw1 < c - RS) { __builtin_amdgcn_s_sleep(4); }   // slot freed by wave1
            asm volatile("" ::: "memory");

            float* slot = s_slots + (size_t)(c & (RS - 1)) * CR * LROW;
            for (int r = 0; r < rows; ++r) {
                const float* src = wp + (size_t)(t0 + r) * LROW + 4 * lane;
                float* dst = slot + r * LROW + 4 * lane;
                if (16 * lane < rowbytes) gl_lds16(src, dst);
                if (half2 && 1024 + 16 * lane < rowbytes) gl_lds16(src + 256, dst + 256);
            }
            if (lane < CR)
                gl_lds4(wpb + t0 + lane, s_pb + (c & (RS - 1)) * CR + lane);

            asm volatile("s_waitcnt vmcnt(0)" ::: "memory");
            __threadfence_block();
            if (lane == 0) vready[c & (RS - 1)] = c;
        }
    }

    __syncthreads();
    if (tid == 0) {
        const double logTd = 27.725887222397812;   // 40*ln2
        const double LN2d  = 0.69314718055994531;
        float aE = s_dumpE[kl];
        float aO = s_dumpO[kl - 1];
        int e0c = s_e0c, e1c = s_e1c;
        double sE = logTd + (double)((kl     >= 256) ? e1c : e0c) * LN2d;
        double sO = logTd + (double)((kl - 1 >= 256) ? e1c : e0c) * LN2d;
        double lE = (aE > 0.f) ? log((double)aE) - sE : -1e300;
        double lO = (aO > 0.f) ? log((double)aO) - sO : -1e300;
        double mx = fmax(lE, lO);
        double ll = (mx < -1e290) ? -745.0 : mx + log(exp(lE - mx) + exp(lO - mx));
        float val = (float)(-ll / ((double)kl * (double)BB));
        atomicAdd(out, val);
    }
}

// ---------------------------------------------------------------------------
// Fallback: original fused kernel (verbatim), used when workspace is too small
// ---------------------------------------------------------------------------
__global__ __launch_bounds__(NW * 64)
void ForwardSumLoss_77378130805413_kernel(const float* __restrict__ attn,
                                          const int* __restrict__ in_lens,
                                          const int* __restrict__ out_lens,
                                          float* __restrict__ out)
{
    __shared__ float s_slots[RS * CR * SLOT_F];   // 133120 B
    __shared__ float s_dumpE[513];
    __shared__ float s_dumpO[512];
    __shared__ float s_bring[BRN];
    __shared__ int   s_ef0[4];
    __shared__ int   s_ready[RS];
    __shared__ int   s_w0, s_w1;
    __shared__ int   s_e0c, s_e1c;

    const int b    = blockIdx.x;
    const int tid  = threadIdx.x;
    const int wave = tid >> 6;
    const int lane = tid & 63;

    int kl = in_lens[b];  kl = kl < 1 ? 1 : (kl > TKK ? TKK : kl);
    int ql = out_lens[b]; ql = ql < 1 ? 1 : (ql > TQQ ? TQQ : ql);
    const int nchunks = (ql + CR - 1) / CR;

    if (tid < RS)  s_ready[tid] = -1;
    if (tid < BRN) s_bring[tid] = 0.f;
    if (tid == 32) s_w0 = -1;
    if (tid == 33) s_w1 = -1;
    __syncthreads();

    volatile int* vready = s_ready;
    volatile int* vw0    = &s_w0;
    volatile int* vw1    = &s_w1;
    volatile int* vEF0   = s_ef0;

    const float T = 1.0995116e12f;   // 2^40

    if (wave == 0) {
        __builtin_amdgcn_s_setprio(3);
        float E[4] = {0,0,0,0}, O[4] = {0,0,0,0};
        int e0c = 0;
        const int base4 = 4 * lane;
        int rdyN = -9, w1s = -9;

        for (int k = 0; k < nchunks; ++k) {
            const int t0   = k * CR;
            const int rows = min(ql - t0, CR);
            if (k >= 2) { while (w1s < k - 2) { w1s = *vw1; } }
            if (rdyN != k) { while (vready[k & (RS - 1)] != k) {} }
            asm volatile("" ::: "memory");
            const float* bp = s_slots + (size_t)(k & (RS - 1)) * CR * SLOT_F;

            if (rows == CR) {
                float4 P[CR]; float PB[CR];
                #pragma unroll
                for (int r = 0; r < CR; ++r) {
                    P[r]  = *(const float4*)(bp + r * SLOT_F + base4);
                    PB[r] = bp[r * SLOT_F + 512];
                }
                rdyN = vready[(k + 1) & (RS - 1)];
                w1s  = *vw1;
                #pragma unroll
                for (int r = 0; r < CR; ++r) {
                    if (k == 0 && r == 0) {
                        E[0] = (lane == 0) ? PB[0]  * T : 0.f;
                        O[0] = (lane == 0) ? P[0].x * T : 0.f;
                    } else {
                        float o_prev = dpp_wave_shr1(O[3], 0.0f);
                        step_quad(P[r], PB[r], o_prev, E, O);
                    }
                    if (r < CR - 1) { if (lane == 63) s_bring[(t0 + r) & (BRN - 1)] = O[3]; }
                }
                float m0 = fmaxf(fmaxf(fmaxf(E[0], E[1]), fmaxf(E[2], E[3])),
                                 fmaxf(fmaxf(O[0], O[1]), fmaxf(O[2], O[3])));
                m0 = wred_max(m0);
                int ef = 0;
                if (m0 > 0.f) ef = 167 - (int)((__float_as_uint(m0) >> 23) & 255);
                float fh = pow2i(ef - (ef >> 1));
                float fl = pow2i(ef >> 1);
                #pragma unroll
                for (int i = 0; i < 4; ++i) { E[i] = (E[i] * fh) * fl; O[i] = (O[i] * fh) * fl; }
                e0c += ef;
                if (lane == 0) vEF0[k & 3] = ef;
                if (lane == 63) s_bring[(t0 + CR - 1) & (BRN - 1)] = O[3];
            } else {
                for (int r = 0; r < rows; ++r) {
                    const float* sq = bp + r * SLOT_F;
                    float4 p = *(const float4*)(sq + base4);
                    float pb = sq[512];
                    if (k == 0 && r == 0) {
                        E[0] = (lane == 0) ? pb  * T : 0.f;
                        O[0] = (lane == 0) ? p.x * T : 0.f;
                    } else {
                        float o_prev = dpp_wave_shr1(O[3], 0.0f);
                        step_quad(p, pb, o_prev, E, O);
                    }
                    if (lane == 63) s_bring[(t0 + r) & (BRN - 1)] = O[3];
                }
            }
            asm volatile("" ::: "memory");
            if (lane == 0) *vw0 = k;
        }
        #pragma unroll
        for (int i = 0; i < 4; ++i) {
            s_dumpE[base4 + i] = E[i];
            s_dumpO[base4 + i] = O[i];
        }
        if (lane == 0) s_e0c = e0c;
    } else if (wave == 1) {
        __builtin_amdgcn_s_setprio(3);
        float E[4] = {0,0,0,0}, O[4] = {0,0,0,0}, e512 = 0.f;
        int e0c = 0, e1c = 0;
        const int base4 = 256 + 4 * lane;
        int w0s = -9;

        for (int k = 0; k < nchunks; ++k) {
            const int t0   = k * CR;
            const int rows = min(ql - t0, CR);
            while (w0s < k) { w0s = *vw0; }
            asm volatile("" ::: "memory");
            const float* bp = s_slots + (size_t)(k & (RS - 1)) * CR * SLOT_F;

            int dE = e1c - e0c;
            dE = dE < -250 ? -250 : (dE > 250 ? 250 : dE);
            const float Ch = pow2i(dE - (dE >> 1));
            const float Cl = pow2i(dE >> 1);

            if (rows == CR) {
                float4 P[CR]; float PB[CR], BND[CR];
                #pragma unroll
                for (int r = 0; r < CR; ++r) {
                    P[r]   = *(const float4*)(bp + r * SLOT_F + base4);
                    PB[r]  = bp[r * SLOT_F + 512];
                    BND[r] = (s_bring[(t0 - 1 + r) & (BRN - 1)] * Ch) * Cl;
                }
                w0s = *vw0;
                #pragma unroll
                for (int r = 0; r < CR; ++r) {
                    float o_prev = dpp_wave_shr1(O[3], 0.0f);
                    o_prev = (lane == 0) ? BND[r] : o_prev;
                    float te = e512 + O[3]; e512 = te * PB[r];
                    step_quad(P[r], PB[r], o_prev, E, O);
                }
                float m1 = fmaxf(fmaxf(fmaxf(E[0], E[1]), fmaxf(E[2], E[3])),
                                 fmaxf(fmaxf(O[0], O[1]), fmaxf(O[2], O[3])));
                m1 = fmaxf(m1, e512);
                m1 = wred_max(m1);
                int ef0k = vEF0[k & 3];
                int ef1  = (m1 > 0.f) ? (167 - (int)((__float_as_uint(m1) >> 23) & 255))
                                      : ef0k;
                float fh = pow2i(ef1 - (ef1 >> 1));
                float fl = pow2i(ef1 >> 1);
                #pragma unroll
                for (int i = 0; i < 4; ++i) { E[i] = (E[i] * fh) * fl; O[i] = (O[i] * fh) * fl; }
                e512 = (e512 * fh) * fl;
                e1c += ef1;
                e0c += ef0k;
            } else {
                for (int r = 0; r < rows; ++r) {
                    const float* sq = bp + r * SLOT_F;
                    float4 p = *(const float4*)(sq + base4);
                    float pb = sq[512];
                    float bnd = (s_bring[(t0 - 1 + r) & (BRN - 1)] * Ch) * Cl;
                    float o_prev = dpp_wave_shr1(O[3], 0.0f);
                    o_prev = (lane == 0) ? bnd : o_prev;
                    float te = e512 + O[3]; e512 = te * pb;
                    step_quad(p, pb, o_prev, E, O);
                }
            }
            asm volatile("" ::: "memory");
            if (lane == 0) *vw1 = k;
        }
        #pragma unroll
        for (int i = 0; i < 4; ++i) {
            s_dumpE[base4 + i] = E[i];
            s_dumpO[base4 + i] = O[i];
        }
        if (lane == 63) s_dumpE[512] = e512;
        if (lane == 0)  s_e1c = e1c;
    } else {
        const int pidx = wave - 2;
        const float* base = attn + (size_t)b * TQQ * TKK;
        const int j0 = 8 * lane;

        for (int c = pidx; c < nchunks; c += NW - 2) {
            const int t0 = c * CR;
            while (*vw1 < c - RS) { __builtin_amdgcn_s_sleep(4); }
            asm volatile("" ::: "memory");

            float4 x0[CR], x1[CR];
            #pragma unroll
            for (int r = 0; r < CR; ++r) {
                x0[r] = make_float4(-1e30f, -1e30f, -1e30f, -1e30f);
                x1[r] = x0[r];
                const int t = t0 + r;
                if (t < ql) {
                    const float* row = base + (size_t)t * TKK;
                    if (j0 < kl)     x0[r] = *(const float4*)(row + j0);
                    if (j0 + 4 < kl) x1[r] = *(const float4*)(row + j0 + 4);
                }
            }
            float* bp = s_slots + (size_t)(c & (RS - 1)) * CR * SLOT_F;
            #pragma unroll
            for (int r = 0; r < CR; ++r) {
                const int t = t0 + r;
                if (t >= ql) continue;
                float va[8] = {x0[r].x, x0[r].y, x0[r].z, x0[r].w,
                               x1[r].x, x1[r].y, x1[r].z, x1[r].w};
                float m = -1.0f;
                #pragma unroll
                for (int cc = 0; cc < 8; ++cc) if (j0 + cc < kl) m = fmaxf(m, va[cc]);
                m = wred_max(m);
                float pv[8]; float vsum = 0.f;
                #pragma unroll
                for (int cc = 0; cc < 8; ++cc) {
                    pv[cc] = (j0 + cc < kl) ? __expf(va[cc] - m) : 0.f;
                    vsum += pv[cc];
                }
                vsum = wred_sum(vsum);
                float vb   = __expf(-1.0f - m);
                float rinv = 1.0f / (vsum + vb);
                float* sp = bp + (size_t)r * SLOT_F;
                *(float4*)(sp + j0)     = make_float4(pv[0]*rinv, pv[1]*rinv, pv[2]*rinv, pv[3]*rinv);
                *(float4*)(sp + j0 + 4) = make_float4(pv[4]*rinv, pv[5]*rinv, pv[6]*rinv, pv[7]*rinv);
                if (lane == 0) sp[512] = vb * rinv;
            }
            __threadfence_block();
            if (lane == 0) vready[c & (RS - 1)] = c;
        }
    }

    __syncthreads();
    if (tid == 0) {
        const double logTd = 27.725887222397812;
        const double LN2d  = 0.69314718055994531;
        float aE = s_dumpE[kl];
        float aO = s_dumpO[kl - 1];
        int e0c = s_e0c, e1c = s_e1c;
        double sE = logTd + (double)((kl     >= 256) ? e1c : e0c) * LN2d;
        double sO = logTd + (double)((kl - 1 >= 256) ? e1c : e0c) * LN2d;
        double lE = (aE > 0.f) ? log((double)aE) - sE : -1e300;
        double lO = (aO > 0.f) ? log((double)aO) - sO : -1e300;
        double mx = fmax(lE, lO);
        double ll = (mx < -1e290) ? -745.0 : mx + log(exp(lE - mx) + exp(lO - mx));
        float val = (float)(-ll / ((double)kl * (double)BB));
        atomicAdd(out, val);
    }
}

extern "C" void kernel_launch(void* const* d_in, const int* in_sizes, int n_in,
                              void* d_out, int out_size, void* d_ws, size_t ws_size,
                              hipStream_t stream) {
    const float* attn     = (const float*)d_in[0];
    const int*   in_lens  = (const int*)d_in[1];
    const int*   out_lens = (const int*)d_in[2];
    float* out = (float*)d_out;
    hipMemsetAsync(out, 0, sizeof(float), stream);

    const size_t need = ((size_t)BB * TQQ * LROW + (size_t)BB * TQQ) * sizeof(float); // ~131.3 MB
    if (d_ws != nullptr && ws_size >= need) {
        float* ws = (float*)d_ws;
        dim3 g1(BB, (TQQ + SMC * CR - 1) / (SMC * CR));   // 32 x 63
        hipLaunchKernelGGL(ForwardSumLoss_77378130805413_softmax,
                           g1, dim3(64 * SMC), 0, stream,
                           attn, in_lens, out_lens, ws);
        hipLaunchKernelGGL(ForwardSumLoss_77378130805413_dp,
                           dim3(BB), dim3(NW * 64), 0, stream,
                           (const float*)ws, in_lens, out_lens, out);
    } else {
        hipLaunchKernelGGL(ForwardSumLoss_77378130805413_kernel,
                           dim3(BB), dim3(NW * 64), 0, stream,
                           attn, in_lens, out_lens, out);
    }
}